// Round 9
// baseline (259.542 us; speedup 1.0000x reference)
//
#include <hip/hip_runtime.h>
#include <hip/hip_bf16.h>

// TupleAveragePredictor: out = sigmoid( relu( [mean(gnn_h[tuples[:,1:]]), gnn_h[triplets[:,2]]] @ W1^T + b1 ) @ W2^T + b2 )
// R9 = R8 with a software-pipelined gather: each step's 10 node-loads split
// into two 5-load buffers, issue/decode interleaved across steps so ~2 batches
// are in flight per wave instead of 1 (R8 showed instr count doesn't matter;
// R5->R6 showed bytes*latency does -> raise per-wave MLP).
// MFMA phase / LDS swizzle / epilogue identical to R8 (245us anchor).

#define NROWS 200000
#define NNODES 100000
#define INF 256
#define KDIM 512
#define HF 512
#define BM 64

typedef __attribute__((ext_vector_type(8))) short short8;
typedef __attribute__((ext_vector_type(4))) float f32x4;
typedef __attribute__((ext_vector_type(2))) float f32x2;

__device__ __align__(16) unsigned short g_hb[NNODES * INF];   // 51.2 MB bf16 (target reads)
__device__ __align__(16) unsigned char  g_h8[NNODES * INF];   // 25.6 MB fp8 e4m3 (avg reads)
__device__ __align__(16) unsigned short g_W1p[HF * KDIM];     // 512 KB fragment-packed W1

__device__ __forceinline__ unsigned short f2bf(float f) {
    unsigned int u = __float_as_uint(f);
    return (unsigned short)((u + 0x7fffu + ((u >> 16) & 1u)) >> 16);
}
__device__ __forceinline__ unsigned long long pk4(float a, float b, float c, float d) {
    return (unsigned long long)f2bf(a) | ((unsigned long long)f2bf(b) << 16)
         | ((unsigned long long)f2bf(c) << 32) | ((unsigned long long)f2bf(d) << 48);
}

// gnn_h fp32 -> bf16 table AND fp8 table, 8 elems/thread (12500 blocks x 256).
__global__ void convert_h_kernel(const float* __restrict__ gnn_h) {
    int i = (blockIdx.x * 256 + threadIdx.x) * 8;
    float4 a = *(const float4*)(gnn_h + i);
    float4 b = *(const float4*)(gnn_h + i + 4);
    ulonglong2 v;
    v.x = pk4(a.x, a.y, a.z, a.w);
    v.y = pk4(b.x, b.y, b.z, b.w);
    *(ulonglong2*)(g_hb + i) = v;
    int w0 = __builtin_amdgcn_cvt_pk_fp8_f32(a.x, a.y, 0, 0);
    w0     = __builtin_amdgcn_cvt_pk_fp8_f32(a.z, a.w, w0, 1);
    int w1 = __builtin_amdgcn_cvt_pk_fp8_f32(b.x, b.y, 0, 0);
    w1     = __builtin_amdgcn_cvt_pk_fp8_f32(b.z, b.w, w1, 1);
    *(uint2*)(g_h8 + i) = make_uint2((unsigned)w0, (unsigned)w1);
}

// W1 -> bf16 packed in B-fragment order (as R5/R6/R8):
// packed[(c*16+ki)*512 + lane*8 + j] = W1[col=c*16+(lane&15)][k=ki*32+(lane>>4)*8+j]
__global__ void pack_w1_kernel(const float* __restrict__ W1) {
    int p = (blockIdx.x * 256 + threadIdx.x) * 4;  // 262144/4 = 65536 thr
    int chunk  = p >> 9;
    int within = p & 511;
    int lane = within >> 3;
    int j0   = within & 7;
    int c  = chunk >> 4, ki = chunk & 15;
    int col = c * 16 + (lane & 15);
    int k   = ki * 32 + (lane >> 4) * 8 + j0;
    float4 v = *(const float4*)(W1 + col * KDIM + k);
    *(unsigned long long*)(g_W1p + p) = pk4(v.x, v.y, v.z, v.w);
}

__global__ __launch_bounds__(512, 4)
void fused_kernel(const int* __restrict__ tuples,
                  const int* __restrict__ triplets,
                  const float* __restrict__ b1,
                  const float* __restrict__ W2,
                  const float* __restrict__ b2,
                  float* __restrict__ out) {
    __shared__ __align__(16) unsigned short x_lds[BM * KDIM];  // 64 KB, swizzled
    __shared__ int idx_lds[BM * 11];
    __shared__ int tgt_lds[BM];
    __shared__ float red[8][BM];

    const int t = threadIdx.x;
    const int g0 = blockIdx.x * BM;
    const int lane = t & 63;
    const int wc = t >> 6;

    // ---- stage indices ----
    for (int i = t; i < BM * 11; i += 512) idx_lds[i] = tuples[g0 * 11 + i];
    if (t < BM) tgt_lds[t] = triplets[(g0 + t) * 3 + 2];
    __syncthreads();

    // ---- gather: software-pipelined. 16 rows/step (32 lanes/row), 4 steps.
    // Each step's 10 avg-loads split into bA[5] / bB[5] (+tgt in B); issue of
    // the NEXT batch precedes decode of the CURRENT one -> ~2 batches/wave in
    // flight. Accumulation order i=0..9 identical to R6/R8 (bit-exact).
    // swizzled LDS: phys = L ^ ((row&7)<<4), L = row*1024 + col*2
    const int rgrp = t >> 5;
    const int l32 = t & 31;
    const unsigned char* h8l = g_h8 + l32 * 8;
    uint2 bA[5], bB[5];
    short8 tb;

#define ISSUE_A(rr)                                                      \
    _Pragma("unroll")                                                    \
    for (int i = 0; i < 5; ++i) {                                        \
        int n = idx_lds[(rr) * 11 + 1 + i];                              \
        n = min(max(n, 0), NNODES - 1);                                  \
        bA[i] = *(const uint2*)(h8l + n * INF);                          \
    }
#define ISSUE_B(rr)                                                      \
    _Pragma("unroll")                                                    \
    for (int i = 0; i < 5; ++i) {                                        \
        int n = idx_lds[(rr) * 11 + 6 + i];                              \
        n = min(max(n, 0), NNODES - 1);                                  \
        bB[i] = *(const uint2*)(h8l + n * INF);                          \
    }                                                                    \
    {                                                                    \
        int tg = tgt_lds[(rr)];                                          \
        tg = min(max(tg, 0), NNODES - 1);                                \
        tb = *(const short8*)(g_hb + tg * INF + l32 * 8);                \
    }
#define DECODE(buf)                                                      \
    _Pragma("unroll")                                                    \
    for (int i = 0; i < 5; ++i) {                                        \
        s0 += __builtin_amdgcn_cvt_pk_f32_fp8((int)buf[i].x, 0);         \
        s1 += __builtin_amdgcn_cvt_pk_f32_fp8((int)buf[i].x, 1);         \
        s2 += __builtin_amdgcn_cvt_pk_f32_fp8((int)buf[i].y, 0);         \
        s3 += __builtin_amdgcn_cvt_pk_f32_fp8((int)buf[i].y, 1);         \
    }

    {
        int r = rgrp;
        ISSUE_A(r)
        #pragma unroll
        for (int step = 0; step < 4; ++step) {
            r = step * 16 + rgrp;
            f32x2 s0 = {0.f, 0.f}, s1 = {0.f, 0.f}, s2 = {0.f, 0.f}, s3 = {0.f, 0.f};
            ISSUE_B(r)
            DECODE(bA)
            if (step < 3) { const int rn = (step + 1) * 16 + rgrp; ISSUE_A(rn) }
            DECODE(bB)
            ulonglong2 avg;
            avg.x = pk4(s0.x * 0.1f, s0.y * 0.1f, s1.x * 0.1f, s1.y * 0.1f);
            avg.y = pk4(s2.x * 0.1f, s2.y * 0.1f, s3.x * 0.1f, s3.y * 0.1f);
            const int x = (r & 7) << 4;
            *(ulonglong2*)((char*)x_lds + ((r * 1024 + l32 * 16) ^ x)) = avg;
            *(short8*)((char*)x_lds + ((r * 1024 + 512 + l32 * 16) ^ x)) = tb;
        }
    }
#undef ISSUE_A
#undef ISSUE_B
#undef DECODE
    __syncthreads();

    // ---- MFMA: wave wc owns h-cols [wc*64, wc*64+64), acc[4][4] (= R8) ----
    const int arow = lane & 15;
    const int kgrp = lane >> 4;

    float b1r[4], w2r[4];
    #pragma unroll
    for (int ct = 0; ct < 4; ++ct) {
        b1r[ct] = b1[wc * 64 + ct * 16 + arow];
        w2r[ct] = W2[wc * 64 + ct * 16 + arow];
    }

    f32x4 acc[4][4];
    #pragma unroll
    for (int rt = 0; rt < 4; ++rt)
        #pragma unroll
        for (int ct = 0; ct < 4; ++ct)
            acc[rt][ct] = (f32x4){0.f, 0.f, 0.f, 0.f};

    const int xsw = (arow & 7) << 4;
    for (int ki = 0; ki < 16; ++ki) {
        short8 a[4];
        #pragma unroll
        for (int rt = 0; rt < 4; ++rt) {
            const int loff = (rt * 16 + arow) * 1024 + ki * 64 + kgrp * 16;
            a[rt] = *(const short8*)((const char*)x_lds + (loff ^ xsw));
        }
        #pragma unroll
        for (int ct = 0; ct < 4; ++ct) {
            const short8 b = *(const short8*)(g_W1p + ((wc * 4 + ct) * 16 + ki) * 512 + lane * 8);
            #pragma unroll
            for (int rt = 0; rt < 4; ++rt)
                acc[rt][ct] = __builtin_amdgcn_mfma_f32_16x16x32_bf16(a[rt], b, acc[rt][ct], 0, 0, 0);
        }
    }

    // ---- epilogue: relu + dot(W2) + reduce + sigmoid ----
    // D mapping: col = wc*64 + ct*16 + (lane&15), row = rt*16 + kgrp*4 + reg
    #pragma unroll
    for (int rt = 0; rt < 4; ++rt) {
        #pragma unroll
        for (int reg = 0; reg < 4; ++reg) {
            float s = 0.f;
            #pragma unroll
            for (int ct = 0; ct < 4; ++ct) {
                float h = acc[rt][ct][reg] + b1r[ct];
                s += fmaxf(h, 0.f) * w2r[ct];
            }
            s += __shfl_xor(s, 1, 64);
            s += __shfl_xor(s, 2, 64);
            s += __shfl_xor(s, 4, 64);
            s += __shfl_xor(s, 8, 64);
            if ((lane & 15) == 0)
                red[wc][rt * 16 + kgrp * 4 + reg] = s;
        }
    }
    __syncthreads();

    if (t < BM) {
        float s = b2[0];
        #pragma unroll
        for (int i = 0; i < 8; ++i) s += red[i][t];
        out[g0 + t] = 1.f / (1.f + expf(-s));
    }
}

extern "C" void kernel_launch(void* const* d_in, const int* in_sizes, int n_in,
                              void* d_out, int out_size, void* d_ws, size_t ws_size,
                              hipStream_t stream) {
    const float* gnn_h    = (const float*)d_in[0];
    const int*   tuples   = (const int*)d_in[1];
    const int*   triplets = (const int*)d_in[2];
    const float* W1       = (const float*)d_in[3];
    const float* b1       = (const float*)d_in[4];
    const float* W2       = (const float*)d_in[5];
    const float* b2       = (const float*)d_in[6];
    float* out = (float*)d_out;

    convert_h_kernel<<<dim3(NNODES * INF / (256 * 8)), dim3(256), 0, stream>>>(gnn_h);
    pack_w1_kernel<<<dim3(HF * KDIM / (256 * 4)), dim3(256), 0, stream>>>(W1);
    fused_kernel<<<dim3(NROWS / BM), dim3(512), 0, stream>>>(
        tuples, triplets, b1, W2, b2, out);
}